// Round 11
// baseline (83.703 us; speedup 1.0000x reference)
//
#include <hip/hip_runtime.h>

typedef unsigned long long u64;
typedef unsigned int u32;
typedef unsigned short u16;
typedef unsigned char u8;

#define S_LEN 2048
#define BATCH 8
#define DMODEL 648

// ONE kernel. Grid (32 chunks, 8 batch) x 512 threads = 256 WGs = 1/CU.
// Each WG owns chunk c (queries q in [64c, 64c+64)) of batch column b:
//   1) build LDS tables: P rows (atomicOr ballot), {S1,S2} pair rows, tokens
//   2) shared scan over blocks w<c (8 waves split token space 8 ways):
//        PB[t0][t] = #{j<64c: src[j-1]==t0 && src[j]==t}   (h1 base)
//        RB[t1][t0] bit w = bigram (t1,t0) occurs in block w (depth>=2 gate)
//        PS1[t0] = sum_t PB[t0][t]  (wave-sum), PU[t] = #{j<64c: src[j]==t}
//   3) each wave answers 8 queries in O(1) LDS lookups + rare-block loop
//      (E ~0.25 blocks/query) and writes its 648 channels.
// Depth rows derive from S2 (shift-2): S3 = (S2<<1)|(S2prev>>63),
// S4 = (S2<<2)|(S2prev>>62) -- same identities verified in R9/R10 (absmax 0).
__global__ __launch_bounds__(512) void fused_kernel(const int* __restrict__ src,
                                                    float* __restrict__ out) {
    __shared__ __align__(16) ulonglong2 Lpair[2048];  // 32 KB {S1,S2}
    __shared__ u64 LP[2048];                          // 16 KB P rows
    __shared__ u32 RBl[4096];                         // 16 KB RB[t1][t0]
    __shared__ u16 PBl[4096];                         //  8 KB PB[t0][t]
    __shared__ u16 PS1l[64];
    __shared__ u16 PUl[64];
    __shared__ u8  Ltok[2048];                        //  2 KB tokens

    const int b = blockIdx.y;
    const int c = 31 - blockIdx.x;     // descending: longest scans start first
    const int tid = threadIdx.x;
    const int lane = tid & 63;
    const int wv = tid >> 6;           // 0..7

    // ---- 1) build ----
    int myt[4];
    #pragma unroll
    for (int k = 0; k < 4; ++k) {
        const int i = tid + 512 * k;
        myt[k] = src[i * BATCH + b];
        Ltok[i] = (u8)myt[k];
        LP[i] = 0;
    }
    __syncthreads();
    #pragma unroll
    for (int k = 0; k < 4; ++k) {
        const int i = tid + 512 * k;
        atomicOr(&LP[(i & ~63) | myt[k]], 1ull << (i & 63));
    }
    __syncthreads();
    #pragma unroll
    for (int k = 0; k < 4; ++k) {
        const int i = tid + 512 * k;
        const u64 m = LP[i];
        const u64 mp = (i >= 64) ? LP[i - 64] : 0ull;
        ulonglong2 pr;
        pr.x = (m << 1) | (mp >> 63);   // S1
        pr.y = (m << 2) | (mp >> 62);   // S2
        Lpair[i] = pr;
    }
    __syncthreads();

    // ---- 2) shared scan over w < c ----
    {
        u32 pb8[8] = {}, rb8[8] = {};
        u32 pu = 0;
        const int tbase = wv << 3;      // this wave's 8 t-slots
        for (int w = 0; w < c; ++w) {
            const int wb = w << 6;
            const u64 pvl = LP[wb + lane];          // per-lane P row
            const u64 s1l = Lpair[wb + lane].x;     // per-lane S1 row
            pu += (u32)__popcll(pvl);
            #pragma unroll
            for (int i = 0; i < 8; ++i) {
                const ulonglong2 pr = Lpair[wb + tbase + i];  // uniform
                pb8[i] += (u32)__popcll(pr.x & pvl);
                rb8[i] |= (u32)((pr.y & s1l) != 0ull) << w;
            }
        }
        #pragma unroll
        for (int i = 0; i < 8; ++i) {
            PBl[((tbase + i) << 6) + lane] = (u16)pb8[i];
            RBl[((tbase + i) << 6) + lane] = rb8[i];
            int s = (int)pb8[i];
            #pragma unroll
            for (int sft = 1; sft < 64; sft <<= 1) s += __shfl_xor(s, sft);
            if (lane == 0) PS1l[tbase + i] = (u16)s;   // PS1 = sum_t PB
        }
        if (wv == 0) PUl[lane] = (u16)pu;
    }
    __syncthreads();

    // ---- 3) queries: wave wv answers q = 64c + wv*8 + k, k=0..7 ----
    const int cbase = c << 6;
    const u64 pvq = LP[cbase + lane];
    const int pul = (int)PUl[lane];

    #pragma unroll 1
    for (int k = 0; k < 8; ++k) {
        const int rem = (wv << 3) + k;       // 0..63
        const int q = cbase + rem;
        const u64 valid = (1ull << rem) - 1ull;   // rem==0 -> 0

        const int t4 = (int)Ltok[q];
        const int t0 = (q >= 1) ? (int)Ltok[q - 1] : 0;  // clamp: dead rows
        const int t1 = (q >= 2) ? (int)Ltok[q - 2] : 0;
        const int t2 = (q >= 3) ? (int)Ltok[q - 3] : 0;
        const int t3 = (q >= 4) ? (int)Ltok[q - 4] : 0;

        const u64 M1p = Lpair[cbase + t0].x & valid;
        int c1 = (int)PS1l[t0] + __popcll(M1p);
        int h1 = (int)PBl[(t0 << 6) + lane] + __popcll(M1p & pvq);
        int cu = pul + __popcll(pvq & valid);

        int c2 = 0, c3 = 0, c4 = 0, h2 = 0, h3 = 0, h4 = 0;
        const u64 M2p = M1p & Lpair[cbase + t1].y;
        if (M2p) {   // in-chunk depths 2-4 (wave-uniform branch, ~1%)
            const u64 cS2  = Lpair[cbase + t2].y;
            const u64 cS2p = c ? Lpair[cbase - 64 + t2].y : 0ull;
            const u64 dS2  = Lpair[cbase + t3].y;
            const u64 dS2p = c ? Lpair[cbase - 64 + t3].y : 0ull;
            const u64 M3p = M2p & ((cS2 << 1) | (cS2p >> 63));
            const u64 M4p = M3p & ((dS2 << 2) | (dS2p >> 62));
            c2 += __popcll(M2p); h2 += __popcll(M2p & pvq);
            c3 += __popcll(M3p); h3 += __popcll(M3p & pvq);
            c4 += __popcll(M4p); h4 += __popcll(M4p & pvq);
        }
        u32 rare = RBl[(t1 << 6) + t0];      // full blocks w<c with the bigram
        while (rare) {                        // E ~0.25 iterations
            const int w = __builtin_ctz(rare);
            rare &= rare - 1;
            const int wb = w << 6;
            const u64 M2 = Lpair[wb + t0].x & Lpair[wb + t1].y;
            const u64 cS2  = Lpair[wb + t2].y;
            const u64 cS2p = w ? Lpair[wb - 64 + t2].y : 0ull;
            const u64 dS2  = Lpair[wb + t3].y;
            const u64 dS2p = w ? Lpair[wb - 64 + t3].y : 0ull;
            const u64 M3 = M2 & ((cS2 << 1) | (cS2p >> 63));
            const u64 M4 = M3 & ((dS2 << 2) | (dS2p >> 62));
            const u64 pvw = LP[wb + lane];
            c2 += __popcll(M2); h2 += __popcll(M2 & pvw);
            c3 += __popcll(M3); h3 += __popcll(M3 & pvw);
            c4 += __popcll(M4); h4 += __popcll(M4 & pvw);
        }

        float* op = out + ((size_t)q * BATCH + b) * DMODEL;
        op[0 * 64 + lane] = (lane == t4) ? 1.f : 0.f;
        op[1 * 64 + lane] = (q >= 1 && lane == t0) ? 1.f : 0.f;
        op[2 * 64 + lane] = (q >= 2 && lane == t1) ? 1.f : 0.f;
        op[3 * 64 + lane] = (q >= 3 && lane == t2) ? 1.f : 0.f;
        op[4 * 64 + lane] = (q >= 4 && lane == t3) ? 1.f : 0.f;
        op[320 + lane] = (float)h1 / (float)(c1 ? c1 : 1);
        op[384 + lane] = (float)h2 / (float)(c2 ? c2 : 1);
        op[448 + lane] = (float)h3 / (float)(c3 ? c3 : 1);
        op[512 + lane] = (float)h4 / (float)(c4 ? c4 : 1);
        op[576 + lane] = (float)cu / (float)(q ? q : 1);
        if (lane < 8) {
            float v = 0.f;
            if (lane == 0) v = (float)c1;
            else if (lane == 1) v = (float)c2;
            else if (lane == 2) v = (float)c3;
            else if (lane == 3) v = (float)c4;
            else if (lane == 4) v = (float)q;
            op[640 + lane] = v;
        }
    }
}

extern "C" void kernel_launch(void* const* d_in, const int* in_sizes, int n_in,
                              void* d_out, int out_size, void* d_ws, size_t ws_size,
                              hipStream_t stream) {
    const int* src = (const int*)d_in[0];
    float* out = (float*)d_out;
    fused_kernel<<<dim3(32, BATCH), 512, 0, stream>>>(src, out);
}